// Round 19
// baseline (518.374 us; speedup 1.0000x reference)
//
#include <hip/hip_runtime.h>
#include <hip/hip_bf16.h>
#include <hip/hip_cooperative_groups.h>

namespace cg = cooperative_groups;

#define N_NODES 100000
#define N_EDGES 1600000
#define NBUCK 196                 // ceil(100000/512) node buckets (512 nodes each)
#define BCAP 12288                // per-bucket pk capacity (avg 8192, +45 sigma)
#define CHUNK 4096                // edges per partition chunk
#define PART_BLOCKS 391           // ceil(1600000/4096)
#define CONV_BLOCKS 6250          // x float4 groups / 256 (fallback prep)
#define XGROUPS 1600000           // float4 groups in x
#define CAP32 32                  // per-bucket LDS list slots in partition
#define QNODES 128                // nodes per csr quarter
#define QCAP 3072                 // LDS csr capacity per quarter
#define MSTRIDE 36                // LDS mean row stride (words): 2-way alias (free)
#define GRID_BLOCKS 512           // 2 blocks/CU: launch_bounds(512,4) caps VGPR=128,
                                  // LDS 2x34.8KB=69.6<=160KB -> co-residency guaranteed
#define NWIN 1563                 // ceil(N_NODES/64) layer windows

// fp32 inputs (R3-vs-R5); bf16 MFMA internals; fp32 out. ws = 256 MiB.
// R18 lesson: 768-block coop launch failed residency on VGPRs (needed <=85);
// R19: 512 blocks + __launch_bounds__(512,4) + error-checked fallback to the
// verified R16 multi-kernel path.

typedef __hip_bfloat16 bf16;
typedef short short8 __attribute__((ext_vector_type(8)));
typedef float f32x4 __attribute__((ext_vector_type(4)));
typedef unsigned int uint;

__device__ __forceinline__ short f2bs(float f) {
    bf16 h = __float2bfloat16(f);
    short s; __builtin_memcpy(&s, &h, 2); return s;
}
__device__ __forceinline__ float lo_bf(uint w) {
    uint v = w << 16; float f; __builtin_memcpy(&f, &v, 4); return f;
}
__device__ __forceinline__ float hi_bf(uint w) {
    uint v = w & 0xFFFF0000u; float f; __builtin_memcpy(&f, &v, 4); return f;
}
__device__ __forceinline__ uint pack2(float a, float b) {
    return (uint)(unsigned short)f2bs(a) | ((uint)(unsigned short)f2bs(b) << 16);
}
__device__ __forceinline__ short8 load8bf(const bf16* __restrict__ p, long idx) {
    return *(const short8*)((const short*)p + idx);
}

// ---- gather-mean into LDS (R16 verified; 512 threads, 64 nodes) --------
__device__ __forceinline__ void gather_mean_lds(
    const bf16* __restrict__ feat, const int2* __restrict__ node_range,
    const int* __restrict__ csr, int nb0, uint* __restrict__ mean_l)
{
    int wave = threadIdx.x >> 6, lane = threadIdx.x & 63;
    int g = lane >> 3, ci = lane & 7;
    int nl = wave * 8 + g;
    int n = nb0 + nl;
    int2 rg = (n < N_NODES) ? node_range[n] : make_int2(0, 0);
    int beg = rg.x, end = rg.y;
    const uint* fw = (const uint*)feat;
    float a0 = 0.f, a1 = 0.f, a2 = 0.f, a3 = 0.f;
    float a4 = 0.f, a5 = 0.f, a6 = 0.f, a7 = 0.f;
    int i = beg;
    for (; i + 7 < end; i += 8) {
        int s0 = csr[i],     s1 = csr[i + 1], s2 = csr[i + 2], s3 = csr[i + 3];
        int s4 = csr[i + 4], s5 = csr[i + 5], s6 = csr[i + 6], s7 = csr[i + 7];
        uint4 w0 = *(const uint4*)(fw + (long)s0 * 32 + ci * 4);
        uint4 w1 = *(const uint4*)(fw + (long)s1 * 32 + ci * 4);
        uint4 w2 = *(const uint4*)(fw + (long)s2 * 32 + ci * 4);
        uint4 w3 = *(const uint4*)(fw + (long)s3 * 32 + ci * 4);
        uint4 w4 = *(const uint4*)(fw + (long)s4 * 32 + ci * 4);
        uint4 w5 = *(const uint4*)(fw + (long)s5 * 32 + ci * 4);
        uint4 w6 = *(const uint4*)(fw + (long)s6 * 32 + ci * 4);
        uint4 w7 = *(const uint4*)(fw + (long)s7 * 32 + ci * 4);
        a0 += lo_bf(w0.x) + lo_bf(w1.x) + lo_bf(w2.x) + lo_bf(w3.x)
            + lo_bf(w4.x) + lo_bf(w5.x) + lo_bf(w6.x) + lo_bf(w7.x);
        a1 += hi_bf(w0.x) + hi_bf(w1.x) + hi_bf(w2.x) + hi_bf(w3.x)
            + hi_bf(w4.x) + hi_bf(w5.x) + hi_bf(w6.x) + hi_bf(w7.x);
        a2 += lo_bf(w0.y) + lo_bf(w1.y) + lo_bf(w2.y) + lo_bf(w3.y)
            + lo_bf(w4.y) + lo_bf(w5.y) + lo_bf(w6.y) + lo_bf(w7.y);
        a3 += hi_bf(w0.y) + hi_bf(w1.y) + hi_bf(w2.y) + hi_bf(w3.y)
            + hi_bf(w4.y) + hi_bf(w5.y) + hi_bf(w6.y) + hi_bf(w7.y);
        a4 += lo_bf(w0.z) + lo_bf(w1.z) + lo_bf(w2.z) + lo_bf(w3.z)
            + lo_bf(w4.z) + lo_bf(w5.z) + lo_bf(w6.z) + lo_bf(w7.z);
        a5 += hi_bf(w0.z) + hi_bf(w1.z) + hi_bf(w2.z) + hi_bf(w3.z)
            + hi_bf(w4.z) + hi_bf(w5.z) + hi_bf(w6.z) + hi_bf(w7.z);
        a6 += lo_bf(w0.w) + lo_bf(w1.w) + lo_bf(w2.w) + lo_bf(w3.w)
            + lo_bf(w4.w) + lo_bf(w5.w) + lo_bf(w6.w) + lo_bf(w7.w);
        a7 += hi_bf(w0.w) + hi_bf(w1.w) + hi_bf(w2.w) + hi_bf(w3.w)
            + hi_bf(w4.w) + hi_bf(w5.w) + hi_bf(w6.w) + hi_bf(w7.w);
    }
    for (; i + 1 < end; i += 2) {
        int s0 = csr[i], s1 = csr[i + 1];
        uint4 w0 = *(const uint4*)(fw + (long)s0 * 32 + ci * 4);
        uint4 w1 = *(const uint4*)(fw + (long)s1 * 32 + ci * 4);
        a0 += lo_bf(w0.x) + lo_bf(w1.x); a1 += hi_bf(w0.x) + hi_bf(w1.x);
        a2 += lo_bf(w0.y) + lo_bf(w1.y); a3 += hi_bf(w0.y) + hi_bf(w1.y);
        a4 += lo_bf(w0.z) + lo_bf(w1.z); a5 += hi_bf(w0.z) + hi_bf(w1.z);
        a6 += lo_bf(w0.w) + lo_bf(w1.w); a7 += hi_bf(w0.w) + hi_bf(w1.w);
    }
    if (i < end) {
        int s = csr[i];
        uint4 w = *(const uint4*)(fw + (long)s * 32 + ci * 4);
        a0 += lo_bf(w.x); a1 += hi_bf(w.x);
        a2 += lo_bf(w.y); a3 += hi_bf(w.y);
        a4 += lo_bf(w.z); a5 += hi_bf(w.z);
        a6 += lo_bf(w.w); a7 += hi_bf(w.w);
    }
    int d = end - beg;
    float inv = d > 0 ? 1.0f / (float)d : 0.0f;
    uint4 qv;
    qv.x = pack2(a0 * inv, a1 * inv);
    qv.y = pack2(a2 * inv, a3 * inv);
    qv.z = pack2(a4 * inv, a5 * inv);
    qv.w = pack2(a6 * inv, a7 * inv);
    *(uint4*)(mean_l + nl * MSTRIDE + ci * 4) = qv;
}

// wlb = [Wl | Wr] bf16, each 4096
__device__ __forceinline__ short8 load_bfrag(
    const bf16* __restrict__ wlb, int f, int c, int quad)
{
    if (c < 2) return load8bf(wlb, (long)f * 64 + c * 32 + quad * 8);
    return load8bf(wlb, 4096 + (long)f * 64 + (c - 2) * 32 + quad * 8);
}

// ======================= cooperative mega kernel ========================
__global__ __launch_bounds__(512, 4) void mega_kernel(
    const float* __restrict__ x, const int* __restrict__ ei,
    const float* __restrict__ W1l, const float* __restrict__ b1l,
    const float* __restrict__ W1r, const float* __restrict__ W2l,
    const float* __restrict__ b2l, const float* __restrict__ W2r,
    const float* __restrict__ Wlin, const float* __restrict__ blin,
    float* __restrict__ out,
    bf16* __restrict__ xb, bf16* __restrict__ h1,
    float* __restrict__ ssrc, float* __restrict__ sdst,
    int2* __restrict__ nrng, int* __restrict__ gcur,
    bf16* __restrict__ wb, int* __restrict__ pk, int* __restrict__ csr)
{
    cg::grid_group grid = cg::this_grid();
    __shared__ int smem[8704];                 // 34.8 KB union for all phases
    const int* src = ei;
    const int* dst = ei + N_EDGES;
    int t = threadIdx.x;
    int bid = blockIdx.x;

    // ---- P0: zero bucket cursors ----
    if (bid == 0 && t < 256) gcur[t] = 0;
    grid.sync();

    // ---- P1: convert x/weights to bf16 + partition edges into pk ----
    {
        for (int i = bid * 512 + t; i < XGROUPS; i += GRID_BLOCKS * 512) {
            float4 v = ((const float4*)x)[i];
            uint2 o;
            o.x = pack2(v.x, v.y);
            o.y = pack2(v.z, v.w);
            ((uint2*)xb)[i] = o;
        }
        if (bid == GRID_BLOCKS - 1) {          // weights (bid >= PART_BLOCKS)
            for (int k = t; k < 16384; k += 512) {
                float vv;
                if (k < 4096)       vv = W1l[k];
                else if (k < 8192)  vv = W1r[k - 4096];
                else if (k < 12288) vv = W2l[k - 8192];
                else                vv = W2r[k - 12288];
                wb[k] = __float2bfloat16(vv);
            }
        }
        if (bid < PART_BLOCKS) {
            int* pl  = smem;                   // 8192
            int* cnt = smem + 8192;            // 256
            int* gb  = smem + 8448;            // 256
            if (t < 256) cnt[t] = 0;
            __syncthreads();
            int e0 = bid * CHUNK;
            for (int i = t; i < CHUNK; i += 512) {
                int e = e0 + i;
                if (e < N_EDGES) {
                    int d = dst[e];
                    int b = d >> 9;
                    int payload = src[e] | ((d & 511) << 17);
                    int p = atomicAdd(&cnt[b], 1);
                    if (p < CAP32) {
                        pl[b * CAP32 + p] = payload;
                    } else {                   // rare overflow (~0.3%)
                        int g = atomicAdd(&gcur[b], 1);
                        if (g < BCAP) pk[b * BCAP + g] = payload;
                    }
                }
            }
            __syncthreads();
            if (t < 256) {
                int c = cnt[t] < CAP32 ? cnt[t] : CAP32;
                gb[t] = c > 0 ? atomicAdd(&gcur[t], c) : 0;
                cnt[t] = c;
            }
            __syncthreads();
            for (int i = t; i < 256 * CAP32; i += 512) {
                int b = i >> 5;
                int pos = i & (CAP32 - 1);
                if (pos < cnt[b]) {
                    int g = gb[b] + pos;
                    if (g < BCAP) pk[b * BCAP + g] = pl[i];
                }
            }
        }
    }
    grid.sync();

    // ---- P2: csr_build (quarter-bucket tasks, R16 verified) ----
    for (int qb = bid; qb < NBUCK * 4; qb += GRID_BLOCKS) {
        int* deg   = smem;                     // 512
        int* scn   = smem + 512;               // 512
        int* cur   = smem + 1024;              // 128
        int* csr_l = smem + 1152;              // 3072
        int b = qb >> 2;
        int q = qb & 3;
        int base = b * BCAP;
        int cnt = gcur[b];
        if (cnt > BCAP) cnt = BCAP;
        deg[t] = 0;
        __syncthreads();
        for (int i = t; i < cnt; i += 512)
            atomicAdd(&deg[pk[base + i] >> 17], 1);
        __syncthreads();
        if (t < 64) {
            int e[8], inc[8], s = 0;
#pragma unroll
            for (int k = 0; k < 8; k++) { e[k] = deg[t * 8 + k]; s += e[k]; inc[k] = s; }
            int run = s;
#pragma unroll
            for (int off = 1; off < 64; off <<= 1) {
                int u = __shfl_up(run, off);
                if (t >= off) run += u;
            }
            int excl = run - s;
#pragma unroll
            for (int k = 0; k < 8; k++) scn[t * 8 + k] = excl + inc[k];
        }
        __syncthreads();
        int hs = q * QNODES;
        int hend = hs + QNODES;
        int hs_excl = scn[hs] - deg[hs];
        int he_excl = (hend < 512) ? (scn[hend] - deg[hend]) : cnt;
        int qcnt = he_excl - hs_excl;
        int excl = scn[t] - deg[t];
        if (t >= hs && t < hend) {
            cur[t - hs] = excl - hs_excl;
            int n = (b << 9) + t;
            if (n < N_NODES) nrng[n] = make_int2(base + excl, base + excl + deg[t]);
        }
        __syncthreads();
        for (int i = t; i < cnt; i += 512) {
            int v = pk[base + i];
            int ld = v >> 17;
            if (ld >= hs && ld < hend) {
                int p = atomicAdd(&cur[ld - hs], 1);
                if (p < QCAP) csr_l[p] = v & 0x1FFFF;
            }
        }
        __syncthreads();
        for (int i = t; i < qcnt && i < QCAP; i += 512)
            csr[base + hs_excl + i] = csr_l[i];
        __syncthreads();
    }
    grid.sync();

    // ---- P3: layer1 (gather->LDS, MFMA) ----
    for (int w = bid; w < NWIN; w += GRID_BLOCKS) {
        uint* mean_l = (uint*)smem;
        int nb0 = w * 64;
        gather_mean_lds(xb, nrng, csr, nb0, mean_l);
        __syncthreads();
        int wave = t >> 6, lane = t & 63;
        if (wave < 4) {
            int quad = lane >> 4, n16 = lane & 15;
            int nb = nb0 + wave * 16;
            int ln = wave * 16 + n16;
            int node_a = nb + n16;
            int na = node_a < N_NODES ? node_a : N_NODES - 1;
            short8 a[4];
#pragma unroll
            for (int c = 0; c < 2; c++)
                a[c] = *(const short8*)(mean_l + ln * MSTRIDE + c * 16 + quad * 4);
#pragma unroll
            for (int c = 0; c < 2; c++)
                a[2 + c] = load8bf(xb, (long)na * 64 + c * 32 + quad * 8);
#pragma unroll
            for (int tt = 0; tt < 4; tt++) {
                int f = 16 * tt + n16;
                f32x4 acc = {0.f, 0.f, 0.f, 0.f};
#pragma unroll
                for (int c = 0; c < 4; c++) {
                    short8 bfr = load_bfrag(wb, f, c, quad);
                    acc = __builtin_amdgcn_mfma_f32_16x16x32_bf16(a[c], bfr, acc, 0, 0, 0);
                }
                float bias = b1l[f];
#pragma unroll
                for (int r = 0; r < 4; r++) {
                    int node = nb + quad * 4 + r;
                    if (node < N_NODES)
                        h1[(long)node * 64 + f] = __float2bfloat16(fmaxf(acc[r] + bias, 0.0f));
                }
            }
        }
        __syncthreads();
    }
    grid.sync();

    // ---- P4: layer2 + edge-scorer projection ----
    for (int w = bid; w < NWIN; w += GRID_BLOCKS) {
        uint* mean_l = (uint*)smem;
        int nb0 = w * 64;
        gather_mean_lds(h1, nrng, csr, nb0, mean_l);
        __syncthreads();
        int wave = t >> 6, lane = t & 63;
        if (wave < 4) {
            int quad = lane >> 4, n16 = lane & 15;
            int nb = nb0 + wave * 16;
            int ln = wave * 16 + n16;
            int node_a = nb + n16;
            int na = node_a < N_NODES ? node_a : N_NODES - 1;
            short8 a[4];
#pragma unroll
            for (int c = 0; c < 2; c++)
                a[c] = *(const short8*)(mean_l + ln * MSTRIDE + c * 16 + quad * 4);
#pragma unroll
            for (int c = 0; c < 2; c++)
                a[2 + c] = load8bf(h1, (long)na * 64 + c * 32 + quad * 8);
            float sa[4] = {0.f, 0.f, 0.f, 0.f};
            float sb[4] = {0.f, 0.f, 0.f, 0.f};
            const bf16* wlb = wb + 8192;
#pragma unroll
            for (int tt = 0; tt < 4; tt++) {
                int f = 16 * tt + n16;
                f32x4 acc = {0.f, 0.f, 0.f, 0.f};
#pragma unroll
                for (int c = 0; c < 4; c++) {
                    short8 bfr = load_bfrag(wlb, f, c, quad);
                    acc = __builtin_amdgcn_mfma_f32_16x16x32_bf16(a[c], bfr, acc, 0, 0, 0);
                }
                float bias = b2l[f];
                float wa = Wlin[f];
                float wbv = Wlin[64 + f];
#pragma unroll
                for (int r = 0; r < 4; r++) {
                    float h = fmaxf(acc[r] + bias, 0.0f);
                    sa[r] += h * wa;
                    sb[r] += h * wbv;
                }
            }
#pragma unroll
            for (int m = 1; m < 16; m <<= 1) {
#pragma unroll
                for (int r = 0; r < 4; r++) {
                    sa[r] += __shfl_xor(sa[r], m);
                    sb[r] += __shfl_xor(sb[r], m);
                }
            }
            if (n16 == 0) {
#pragma unroll
                for (int r = 0; r < 4; r++) {
                    int node = nb + quad * 4 + r;
                    if (node < N_NODES) { ssrc[node] = sa[r]; sdst[node] = sb[r]; }
                }
            }
        }
        __syncthreads();
    }
    grid.sync();

    // ---- P5: edge scores ----
    for (int i = bid * 512 + t; i < N_EDGES / 4; i += GRID_BLOCKS * 512) {
        int4 s4 = ((const int4*)src)[i];
        int4 d4 = ((const int4*)dst)[i];
        float b = blin[0];
        float4 o;
        o.x = ssrc[s4.x] + sdst[d4.x] + b;
        o.y = ssrc[s4.y] + sdst[d4.y] + b;
        o.z = ssrc[s4.z] + sdst[d4.z] + b;
        o.w = ssrc[s4.w] + sdst[d4.w] + b;
        ((float4*)out)[i] = o;
    }
}

// ======================= fallback path (R16, verified 235us) ============
__global__ __launch_bounds__(256) void prep_kernel(
    const float* __restrict__ x, bf16* __restrict__ xb,
    const float* __restrict__ W1l, const float* __restrict__ W1r,
    const float* __restrict__ W2l, const float* __restrict__ W2r,
    bf16* __restrict__ wb,
    const int* __restrict__ src, const int* __restrict__ dst,
    int* __restrict__ gcur, int* __restrict__ pk)
{
    __shared__ int pl[256 * CAP32];
    __shared__ int cnt[256], gb[256];
    int t = threadIdx.x;

    if (blockIdx.x >= PART_BLOCKS) {
        int cb = blockIdx.x - PART_BLOCKS;
        int i = cb * 256 + t;
        float4 v = ((const float4*)x)[i];
        uint2 o;
        o.x = pack2(v.x, v.y);
        o.y = pack2(v.z, v.w);
        ((uint2*)xb)[i] = o;
        if (cb == 0) {
            for (int k = t; k < 16384; k += 256) {
                float vv;
                if (k < 4096)       vv = W1l[k];
                else if (k < 8192)  vv = W1r[k - 4096];
                else if (k < 12288) vv = W2l[k - 8192];
                else                vv = W2r[k - 12288];
                wb[k] = __float2bfloat16(vv);
            }
        }
        return;
    }

    cnt[t] = 0;
    __syncthreads();
    int e0 = blockIdx.x * CHUNK;
    for (int i = t; i < CHUNK; i += 256) {
        int e = e0 + i;
        if (e < N_EDGES) {
            int d = dst[e];
            int b = d >> 9;
            int payload = src[e] | ((d & 511) << 17);
            int p = atomicAdd(&cnt[b], 1);
            if (p < CAP32) {
                pl[b * CAP32 + p] = payload;
            } else {
                int g = atomicAdd(&gcur[b], 1);
                if (g < BCAP) pk[b * BCAP + g] = payload;
            }
        }
    }
    __syncthreads();
    {
        int c = cnt[t] < CAP32 ? cnt[t] : CAP32;
        gb[t] = c > 0 ? atomicAdd(&gcur[t], c) : 0;
        cnt[t] = c;
    }
    __syncthreads();
    for (int i = t; i < 256 * CAP32; i += 256) {
        int b = i >> 5;
        int pos = i & (CAP32 - 1);
        if (pos < cnt[b]) {
            int g = gb[b] + pos;
            if (g < BCAP) pk[b * BCAP + g] = pl[i];
        }
    }
}

__global__ __launch_bounds__(512) void csr_build(
    const int* __restrict__ gcur, const int* __restrict__ pk,
    int* __restrict__ csr, int2* __restrict__ node_range)
{
    __shared__ int deg[512], scn[512];
    __shared__ int cur[QNODES];
    __shared__ int csr_l[QCAP];
    int t = threadIdx.x;
    int b = blockIdx.x >> 2;
    int q = blockIdx.x & 3;
    int base = b * BCAP;
    int cnt = gcur[b];
    if (cnt > BCAP) cnt = BCAP;
    deg[t] = 0;
    __syncthreads();
    for (int i = t; i < cnt; i += 512)
        atomicAdd(&deg[pk[base + i] >> 17], 1);
    __syncthreads();
    if (t < 64) {
        int e[8], inc[8], s = 0;
#pragma unroll
        for (int k = 0; k < 8; k++) { e[k] = deg[t * 8 + k]; s += e[k]; inc[k] = s; }
        int run = s;
#pragma unroll
        for (int off = 1; off < 64; off <<= 1) {
            int u = __shfl_up(run, off);
            if (t >= off) run += u;
        }
        int excl = run - s;
#pragma unroll
        for (int k = 0; k < 8; k++) scn[t * 8 + k] = excl + inc[k];
    }
    __syncthreads();
    int hs = q * QNODES;
    int hend = hs + QNODES;
    int hs_excl = scn[hs] - deg[hs];
    int he_excl = (hend < 512) ? (scn[hend] - deg[hend]) : cnt;
    int qcnt = he_excl - hs_excl;
    int excl = scn[t] - deg[t];
    if (t >= hs && t < hend) {
        cur[t - hs] = excl - hs_excl;
        int n = (b << 9) + t;
        if (n < N_NODES) node_range[n] = make_int2(base + excl, base + excl + deg[t]);
    }
    __syncthreads();
    for (int i = t; i < cnt; i += 512) {
        int v = pk[base + i];
        int ld = v >> 17;
        if (ld >= hs && ld < hend) {
            int p = atomicAdd(&cur[ld - hs], 1);
            if (p < QCAP) csr_l[p] = v & 0x1FFFF;
        }
    }
    __syncthreads();
    for (int i = t; i < qcnt && i < QCAP; i += 512)
        csr[base + hs_excl + i] = csr_l[i];
}

__global__ __launch_bounds__(512) void layer1_fused(
    const bf16* __restrict__ xb, const int2* __restrict__ nrng,
    const int* __restrict__ csr, const bf16* __restrict__ wlb,
    const float* __restrict__ bl, bf16* __restrict__ h_out)
{
    __shared__ uint mean_l[64 * MSTRIDE];
    int nb0 = blockIdx.x * 64;
    gather_mean_lds(xb, nrng, csr, nb0, mean_l);
    __syncthreads();
    int tid = threadIdx.x;
    int wave = tid >> 6, lane = tid & 63;
    if (wave >= 4) return;
    int quad = lane >> 4, n16 = lane & 15;
    int nb = nb0 + wave * 16;
    int ln = wave * 16 + n16;

    int node_a = nb + n16;
    int na = node_a < N_NODES ? node_a : N_NODES - 1;
    short8 a[4];
#pragma unroll
    for (int c = 0; c < 2; c++)
        a[c] = *(const short8*)(mean_l + ln * MSTRIDE + c * 16 + quad * 4);
#pragma unroll
    for (int c = 0; c < 2; c++)
        a[2 + c] = load8bf(xb, (long)na * 64 + c * 32 + quad * 8);

#pragma unroll
    for (int t = 0; t < 4; t++) {
        int f = 16 * t + n16;
        f32x4 acc = {0.f, 0.f, 0.f, 0.f};
#pragma unroll
        for (int c = 0; c < 4; c++) {
            short8 bfr = load_bfrag(wlb, f, c, quad);
            acc = __builtin_amdgcn_mfma_f32_16x16x32_bf16(a[c], bfr, acc, 0, 0, 0);
        }
        float bias = bl[f];
#pragma unroll
        for (int r = 0; r < 4; r++) {
            int node = nb + quad * 4 + r;
            if (node < N_NODES)
                h_out[(long)node * 64 + f] = __float2bfloat16(fmaxf(acc[r] + bias, 0.0f));
        }
    }
}

__global__ __launch_bounds__(512) void layer2_fused(
    const bf16* __restrict__ h1, const int2* __restrict__ nrng,
    const int* __restrict__ csr, const bf16* __restrict__ wlb,
    const float* __restrict__ bl, const float* __restrict__ Wlin,
    float* __restrict__ s_src, float* __restrict__ s_dst)
{
    __shared__ uint mean_l[64 * MSTRIDE];
    int nb0 = blockIdx.x * 64;
    gather_mean_lds(h1, nrng, csr, nb0, mean_l);
    __syncthreads();
    int tid = threadIdx.x;
    int wave = tid >> 6, lane = tid & 63;
    if (wave >= 4) return;
    int quad = lane >> 4, n16 = lane & 15;
    int nb = nb0 + wave * 16;
    int ln = wave * 16 + n16;

    int node_a = nb + n16;
    int na = node_a < N_NODES ? node_a : N_NODES - 1;
    short8 a[4];
#pragma unroll
    for (int c = 0; c < 2; c++)
        a[c] = *(const short8*)(mean_l + ln * MSTRIDE + c * 16 + quad * 4);
#pragma unroll
    for (int c = 0; c < 2; c++)
        a[2 + c] = load8bf(h1, (long)na * 64 + c * 32 + quad * 8);

    float sa[4] = {0.f, 0.f, 0.f, 0.f};
    float sb[4] = {0.f, 0.f, 0.f, 0.f};
#pragma unroll
    for (int t = 0; t < 4; t++) {
        int f = 16 * t + n16;
        f32x4 acc = {0.f, 0.f, 0.f, 0.f};
#pragma unroll
        for (int c = 0; c < 4; c++) {
            short8 bfr = load_bfrag(wlb, f, c, quad);
            acc = __builtin_amdgcn_mfma_f32_16x16x32_bf16(a[c], bfr, acc, 0, 0, 0);
        }
        float bias = bl[f];
        float wa = Wlin[f];
        float wb = Wlin[64 + f];
#pragma unroll
        for (int r = 0; r < 4; r++) {
            float h = fmaxf(acc[r] + bias, 0.0f);
            sa[r] += h * wa;
            sb[r] += h * wb;
        }
    }
#pragma unroll
    for (int m = 1; m < 16; m <<= 1) {
#pragma unroll
        for (int r = 0; r < 4; r++) {
            sa[r] += __shfl_xor(sa[r], m);
            sb[r] += __shfl_xor(sb[r], m);
        }
    }
    if (n16 == 0) {
#pragma unroll
        for (int r = 0; r < 4; r++) {
            int node = nb + quad * 4 + r;
            if (node < N_NODES) { s_src[node] = sa[r]; s_dst[node] = sb[r]; }
        }
    }
}

__global__ __launch_bounds__(256) void edge_out_kernel(
    const int* __restrict__ src, const int* __restrict__ dst,
    const float* __restrict__ s_src, const float* __restrict__ s_dst,
    const float* __restrict__ blin, float* __restrict__ out)
{
    int i = blockIdx.x * 256 + threadIdx.x;
    if (i >= N_EDGES / 4) return;
    int4 s4 = ((const int4*)src)[i];
    int4 d4 = ((const int4*)dst)[i];
    float b = blin[0];
    float4 o;
    o.x = s_src[s4.x] + s_dst[d4.x] + b;
    o.y = s_src[s4.y] + s_dst[d4.y] + b;
    o.z = s_src[s4.z] + s_dst[d4.z] + b;
    o.w = s_src[s4.w] + s_dst[d4.w] + b;
    ((float4*)out)[i] = o;
}

extern "C" void kernel_launch(void* const* d_in, const int* in_sizes, int n_in,
                              void* d_out, int out_size, void* d_ws, size_t ws_size,
                              hipStream_t stream) {
    const float* x    = (const float*)d_in[0];
    const int*   ei   = (const int*)d_in[1];
    const float* W1l  = (const float*)d_in[2];
    const float* b1l  = (const float*)d_in[3];
    const float* W1r  = (const float*)d_in[4];
    const float* W2l  = (const float*)d_in[5];
    const float* b2l  = (const float*)d_in[6];
    const float* W2r  = (const float*)d_in[7];
    const float* Wlin = (const float*)d_in[8];
    const float* blin = (const float*)d_in[9];
    float* out = (float*)d_out;

    const int* src = ei;
    const int* dst = ei + N_EDGES;

    // Workspace (~47 MB of 256 MiB; every byte read is written first)
    char* w = (char*)d_ws;
    bf16*  xb    = (bf16*)w;  w += (size_t)N_NODES * 64 * 2;   // 12.8 MB
    bf16*  h1    = (bf16*)w;  w += (size_t)N_NODES * 64 * 2;   // 12.8 MB
    float* ssrc  = (float*)w; w += (size_t)N_NODES * 4;
    float* sdst  = (float*)w; w += (size_t)N_NODES * 4;
    int2*  nrng  = (int2*)w;  w += (size_t)N_NODES * 8;        // 0.8 MB
    int*   gcur  = (int*)w;   w += 256 * 4;
    bf16*  wb    = (bf16*)w;  w += 16384 * 2;                  // 32 KB
    int*   pk    = (int*)w;   w += (size_t)NBUCK * BCAP * 4;   // 9.6 MB
    int*   csr   = (int*)w;   w += (size_t)NBUCK * BCAP * 4;   // 9.6 MB

    void* args[] = {
        (void*)&x, (void*)&ei, (void*)&W1l, (void*)&b1l, (void*)&W1r,
        (void*)&W2l, (void*)&b2l, (void*)&W2r, (void*)&Wlin, (void*)&blin,
        (void*)&out, (void*)&xb, (void*)&h1, (void*)&ssrc, (void*)&sdst,
        (void*)&nrng, (void*)&gcur, (void*)&wb, (void*)&pk, (void*)&csr
    };
    hipError_t err = hipLaunchCooperativeKernel((const void*)mega_kernel,
                                                dim3(GRID_BLOCKS), dim3(512),
                                                args, 0, stream);
    if (err != hipSuccess) {
        // Fallback: verified R16 multi-kernel path (identical outputs)
        const int prep_blocks  = PART_BLOCKS + CONV_BLOCKS;
        const int csr_blocks   = NBUCK * 4;
        const int fused_blocks = (N_NODES + 63) / 64;
        const int eo_blocks    = (N_EDGES / 4 + 255) / 256;
        (void)hipMemsetAsync(gcur, 0, 256 * 4, stream);
        prep_kernel<<<prep_blocks, 256, 0, stream>>>(
            x, xb, W1l, W1r, W2l, W2r, wb, src, dst, gcur, pk);
        csr_build<<<csr_blocks, 512, 0, stream>>>(gcur, pk, csr, nrng);
        layer1_fused<<<fused_blocks, 512, 0, stream>>>(xb, nrng, csr, wb, b1l, h1);
        layer2_fused<<<fused_blocks, 512, 0, stream>>>(h1, nrng, csr, wb + 8192, b2l, Wlin, ssrc, sdst);
        edge_out_kernel<<<eo_blocks, 256, 0, stream>>>(src, dst, ssrc, sdst, blin, out);
    }
}

// Round 20
// 234.839 us; speedup vs baseline: 2.2074x; 2.2074x over previous
//
#include <hip/hip_runtime.h>
#include <hip/hip_bf16.h>

#define N_NODES 100000
#define N_EDGES 1600000
#define NBUCK 196                 // ceil(100000/512) node buckets (512 nodes each)
#define BCAP 12288                // per-bucket pk capacity (avg 8192, +45 sigma)
#define CHUNK 4096                // edges per partition block
#define PART_BLOCKS 391           // ceil(1600000/4096)
#define CONV_BLOCKS 6250          // x float4 groups / 256
#define CAP32 32                  // per-bucket LDS list slots in partition
#define QNODES 128                // nodes per csr_build block (512/4)
#define QCAP 3072                 // LDS csr capacity per quarter (avg 2048, +22 sigma)
#define MSTRIDE 36                // LDS mean row stride (words): 2-way alias (free)

// fp32 inputs (confirmed R3-vs-R5); bf16 MFMA internals; fp32 out.
// Session lessons baked in:
//  R14: identity node->slot mapping (scrambling scatters self/C-writes).
//  R17: LDS neighbor lists at stride 96 words -> bank chaos; csr round-trip
//       through global is cheaper.
//  R18/R19: cooperative mega-kernel fusion regresses ~2x — LDS union forces
//       2 blocks/CU for all phases, halving gather-phase occupancy and
//       doubling FETCH. Multi-kernel R16 structure is the plateau: gather is
//       latency-bound at the structural FETCH floor (8 XCDs x 12.8 MB).

typedef __hip_bfloat16 bf16;
typedef short short8 __attribute__((ext_vector_type(8)));
typedef float f32x4 __attribute__((ext_vector_type(4)));
typedef unsigned int uint;

__device__ __forceinline__ short f2bs(float f) {
    bf16 h = __float2bfloat16(f);
    short s; __builtin_memcpy(&s, &h, 2); return s;
}
__device__ __forceinline__ float lo_bf(uint w) {
    uint v = w << 16; float f; __builtin_memcpy(&f, &v, 4); return f;
}
__device__ __forceinline__ float hi_bf(uint w) {
    uint v = w & 0xFFFF0000u; float f; __builtin_memcpy(&f, &v, 4); return f;
}
__device__ __forceinline__ uint pack2(float a, float b) {
    return (uint)(unsigned short)f2bs(a) | ((uint)(unsigned short)f2bs(b) << 16);
}
__device__ __forceinline__ short8 load8bf(const bf16* __restrict__ p, long idx) {
    return *(const short8*)((const short*)p + idx);
}

// ---- prep: partition (blocks 0..390) + x/weight convert (rest) ---------
// Single-pass LDS bucket lists (32 slots) + global overflow via gcur
// (disjoint atomic reservation). gcur[b] ends as the exact bucket count.
// Payload: src (17b) | local dst (9b) << 17.
__global__ __launch_bounds__(256) void prep_kernel(
    const float* __restrict__ x, bf16* __restrict__ xb,
    const float* __restrict__ W1l, const float* __restrict__ W1r,
    const float* __restrict__ W2l, const float* __restrict__ W2r,
    bf16* __restrict__ wb,
    const int* __restrict__ src, const int* __restrict__ dst,
    int* __restrict__ gcur, int* __restrict__ pk)
{
    __shared__ int pl[256 * CAP32];          // 32 KB
    __shared__ int cnt[256], gb[256];
    int t = threadIdx.x;

    if (blockIdx.x >= PART_BLOCKS) {         // conversion block
        int cb = blockIdx.x - PART_BLOCKS;   // 0..6249
        int i = cb * 256 + t;                // float4 group (1.6M exact)
        float4 v = ((const float4*)x)[i];
        uint2 o;
        o.x = pack2(v.x, v.y);
        o.y = pack2(v.z, v.w);
        ((uint2*)xb)[i] = o;
        if (cb == 0) {
            for (int k = t; k < 16384; k += 256) {
                float vv;
                if (k < 4096)       vv = W1l[k];
                else if (k < 8192)  vv = W1r[k - 4096];
                else if (k < 12288) vv = W2l[k - 8192];
                else                vv = W2r[k - 12288];
                wb[k] = __float2bfloat16(vv);
            }
        }
        return;
    }

    cnt[t] = 0;
    __syncthreads();
    int e0 = blockIdx.x * CHUNK;
    for (int i = t; i < CHUNK; i += 256) {
        int e = e0 + i;
        if (e < N_EDGES) {
            int d = dst[e];
            int b = d >> 9;
            int payload = src[e] | ((d & 511) << 17);
            int p = atomicAdd(&cnt[b], 1);
            if (p < CAP32) {
                pl[b * CAP32 + p] = payload;
            } else {                          // rare overflow (~0.3% of edges)
                int g = atomicAdd(&gcur[b], 1);
                if (g < BCAP) pk[b * BCAP + g] = payload;
            }
        }
    }
    __syncthreads();
    {
        int c = cnt[t] < CAP32 ? cnt[t] : CAP32;
        gb[t] = c > 0 ? atomicAdd(&gcur[t], c) : 0;
        cnt[t] = c;
    }
    __syncthreads();
    for (int i = t; i < 256 * CAP32; i += 256) {
        int b = i >> 5;
        int pos = i & (CAP32 - 1);
        if (pos < cnt[b]) {
            int g = gb[b] + pos;
            if (g < BCAP) pk[b * BCAP + g] = pl[i];
        }
    }
}

// ---- csr_build: quarter-bucket blocks (784) ----------------------------
// Block (b, q) reads bucket b's pk (sequential, L2-shared across quarters),
// full 512-deg hist + wave scan, then sorts only its 128 nodes into LDS and
// writes its csr segment + node ranges sequentially.
__global__ __launch_bounds__(512) void csr_build(
    const int* __restrict__ gcur, const int* __restrict__ pk,
    int* __restrict__ csr, int2* __restrict__ node_range)
{
    __shared__ int deg[512], scn[512];
    __shared__ int cur[QNODES];
    __shared__ int csr_l[QCAP];
    int t = threadIdx.x;
    int b = blockIdx.x >> 2;
    int q = blockIdx.x & 3;
    int base = b * BCAP;
    int cnt = gcur[b];                  // exact bucket count
    if (cnt > BCAP) cnt = BCAP;
    deg[t] = 0;
    __syncthreads();
    for (int i = t; i < cnt; i += 512)
        atomicAdd(&deg[pk[base + i] >> 17], 1);
    __syncthreads();
    // single-wave shfl scan of 512 counts: 8 elems/lane (inclusive)
    if (t < 64) {
        int e[8], inc[8], s = 0;
#pragma unroll
        for (int k = 0; k < 8; k++) { e[k] = deg[t * 8 + k]; s += e[k]; inc[k] = s; }
        int run = s;
#pragma unroll
        for (int off = 1; off < 64; off <<= 1) {
            int u = __shfl_up(run, off);
            if (t >= off) run += u;
        }
        int excl = run - s;
#pragma unroll
        for (int k = 0; k < 8; k++) scn[t * 8 + k] = excl + inc[k];
    }
    __syncthreads();
    int hs = q * QNODES;
    int hend = hs + QNODES;
    int hs_excl = scn[hs] - deg[hs];
    int he_excl = (hend < 512) ? (scn[hend] - deg[hend]) : cnt;
    int qcnt = he_excl - hs_excl;
    int excl = scn[t] - deg[t];
    if (t >= hs && t < hend) {
        cur[t - hs] = excl - hs_excl;
        int n = (b << 9) + t;
        if (n < N_NODES) node_range[n] = make_int2(base + excl, base + excl + deg[t]);
    }
    __syncthreads();
    for (int i = t; i < cnt; i += 512) {
        int v = pk[base + i];
        int ld = v >> 17;
        if (ld >= hs && ld < hend) {
            int p = atomicAdd(&cur[ld - hs], 1);
            if (p < QCAP) csr_l[p] = v & 0x1FFFF;
        }
    }
    __syncthreads();
    for (int i = t; i < qcnt && i < QCAP; i += 512)
        csr[base + hs_excl + i] = csr_l[i];
}

// ---- Fused layers: phase 1 gather-mean -> LDS, phase 2 MFMA ------------
// Identity slots. Gather: 8 lanes/node, lane=16B chunk, unroll-8.

__device__ __forceinline__ void gather_mean_lds(
    const bf16* __restrict__ feat, const int2* __restrict__ node_range,
    const int* __restrict__ csr, int nb0, uint* __restrict__ mean_l)
{
    int wave = threadIdx.x >> 6, lane = threadIdx.x & 63;
    int g = lane >> 3, ci = lane & 7;
    int nl = wave * 8 + g;
    int n = nb0 + nl;
    int2 rg = (n < N_NODES) ? node_range[n] : make_int2(0, 0);
    int beg = rg.x, end = rg.y;
    const uint* fw = (const uint*)feat;
    float a0 = 0.f, a1 = 0.f, a2 = 0.f, a3 = 0.f;
    float a4 = 0.f, a5 = 0.f, a6 = 0.f, a7 = 0.f;
    int i = beg;
    for (; i + 7 < end; i += 8) {                  // 8 rows in flight per lane
        int s0 = csr[i],     s1 = csr[i + 1], s2 = csr[i + 2], s3 = csr[i + 3];
        int s4 = csr[i + 4], s5 = csr[i + 5], s6 = csr[i + 6], s7 = csr[i + 7];
        uint4 w0 = *(const uint4*)(fw + (long)s0 * 32 + ci * 4);
        uint4 w1 = *(const uint4*)(fw + (long)s1 * 32 + ci * 4);
        uint4 w2 = *(const uint4*)(fw + (long)s2 * 32 + ci * 4);
        uint4 w3 = *(const uint4*)(fw + (long)s3 * 32 + ci * 4);
        uint4 w4 = *(const uint4*)(fw + (long)s4 * 32 + ci * 4);
        uint4 w5 = *(const uint4*)(fw + (long)s5 * 32 + ci * 4);
        uint4 w6 = *(const uint4*)(fw + (long)s6 * 32 + ci * 4);
        uint4 w7 = *(const uint4*)(fw + (long)s7 * 32 + ci * 4);
        a0 += lo_bf(w0.x) + lo_bf(w1.x) + lo_bf(w2.x) + lo_bf(w3.x)
            + lo_bf(w4.x) + lo_bf(w5.x) + lo_bf(w6.x) + lo_bf(w7.x);
        a1 += hi_bf(w0.x) + hi_bf(w1.x) + hi_bf(w2.x) + hi_bf(w3.x)
            + hi_bf(w4.x) + hi_bf(w5.x) + hi_bf(w6.x) + hi_bf(w7.x);
        a2 += lo_bf(w0.y) + lo_bf(w1.y) + lo_bf(w2.y) + lo_bf(w3.y)
            + lo_bf(w4.y) + lo_bf(w5.y) + lo_bf(w6.y) + lo_bf(w7.y);
        a3 += hi_bf(w0.y) + hi_bf(w1.y) + hi_bf(w2.y) + hi_bf(w3.y)
            + hi_bf(w4.y) + hi_bf(w5.y) + hi_bf(w6.y) + hi_bf(w7.y);
        a4 += lo_bf(w0.z) + lo_bf(w1.z) + lo_bf(w2.z) + lo_bf(w3.z)
            + lo_bf(w4.z) + lo_bf(w5.z) + lo_bf(w6.z) + lo_bf(w7.z);
        a5 += hi_bf(w0.z) + hi_bf(w1.z) + hi_bf(w2.z) + hi_bf(w3.z)
            + hi_bf(w4.z) + hi_bf(w5.z) + hi_bf(w6.z) + hi_bf(w7.z);
        a6 += lo_bf(w0.w) + lo_bf(w1.w) + lo_bf(w2.w) + lo_bf(w3.w)
            + lo_bf(w4.w) + lo_bf(w5.w) + lo_bf(w6.w) + lo_bf(w7.w);
        a7 += hi_bf(w0.w) + hi_bf(w1.w) + hi_bf(w2.w) + hi_bf(w3.w)
            + hi_bf(w4.w) + hi_bf(w5.w) + hi_bf(w6.w) + hi_bf(w7.w);
    }
    for (; i + 1 < end; i += 2) {
        int s0 = csr[i], s1 = csr[i + 1];
        uint4 w0 = *(const uint4*)(fw + (long)s0 * 32 + ci * 4);
        uint4 w1 = *(const uint4*)(fw + (long)s1 * 32 + ci * 4);
        a0 += lo_bf(w0.x) + lo_bf(w1.x); a1 += hi_bf(w0.x) + hi_bf(w1.x);
        a2 += lo_bf(w0.y) + lo_bf(w1.y); a3 += hi_bf(w0.y) + hi_bf(w1.y);
        a4 += lo_bf(w0.z) + lo_bf(w1.z); a5 += hi_bf(w0.z) + hi_bf(w1.z);
        a6 += lo_bf(w0.w) + lo_bf(w1.w); a7 += hi_bf(w0.w) + hi_bf(w1.w);
    }
    if (i < end) {
        int s = csr[i];
        uint4 w = *(const uint4*)(fw + (long)s * 32 + ci * 4);
        a0 += lo_bf(w.x); a1 += hi_bf(w.x);
        a2 += lo_bf(w.y); a3 += hi_bf(w.y);
        a4 += lo_bf(w.z); a5 += hi_bf(w.z);
        a6 += lo_bf(w.w); a7 += hi_bf(w.w);
    }
    int d = end - beg;
    float inv = d > 0 ? 1.0f / (float)d : 0.0f;
    uint4 qv;
    qv.x = pack2(a0 * inv, a1 * inv);
    qv.y = pack2(a2 * inv, a3 * inv);
    qv.z = pack2(a4 * inv, a5 * inv);
    qv.w = pack2(a6 * inv, a7 * inv);
    *(uint4*)(mean_l + nl * MSTRIDE + ci * 4) = qv;
}

// wlb = [Wl | Wr] bf16, each 4096
__device__ __forceinline__ short8 load_bfrag(
    const bf16* __restrict__ wlb, int f, int c, int quad)
{
    if (c < 2) return load8bf(wlb, (long)f * 64 + c * 32 + quad * 8);
    return load8bf(wlb, 4096 + (long)f * 64 + (c - 2) * 32 + quad * 8);
}

__global__ __launch_bounds__(512) void layer1_fused(
    const bf16* __restrict__ xb, const int2* __restrict__ nrng,
    const int* __restrict__ csr, const bf16* __restrict__ wlb,
    const float* __restrict__ bl, bf16* __restrict__ h_out)
{
    __shared__ uint mean_l[64 * MSTRIDE];
    int nb0 = blockIdx.x * 64;
    gather_mean_lds(xb, nrng, csr, nb0, mean_l);
    __syncthreads();
    int tid = threadIdx.x;
    int wave = tid >> 6, lane = tid & 63;
    if (wave >= 4) return;
    int quad = lane >> 4, n16 = lane & 15;
    int nb = nb0 + wave * 16;
    int ln = wave * 16 + n16;

    int node_a = nb + n16;
    int na = node_a < N_NODES ? node_a : N_NODES - 1;
    short8 a[4];
#pragma unroll
    for (int c = 0; c < 2; c++)
        a[c] = *(const short8*)(mean_l + ln * MSTRIDE + c * 16 + quad * 4);
#pragma unroll
    for (int c = 0; c < 2; c++)
        a[2 + c] = load8bf(xb, (long)na * 64 + c * 32 + quad * 8);

#pragma unroll
    for (int t = 0; t < 4; t++) {
        int f = 16 * t + n16;
        f32x4 acc = {0.f, 0.f, 0.f, 0.f};
#pragma unroll
        for (int c = 0; c < 4; c++) {
            short8 bfr = load_bfrag(wlb, f, c, quad);
            acc = __builtin_amdgcn_mfma_f32_16x16x32_bf16(a[c], bfr, acc, 0, 0, 0);
        }
        float bias = bl[f];
#pragma unroll
        for (int r = 0; r < 4; r++) {
            int node = nb + quad * 4 + r;
            if (node < N_NODES)
                h_out[(long)node * 64 + f] = __float2bfloat16(fmaxf(acc[r] + bias, 0.0f));
        }
    }
}

__global__ __launch_bounds__(512) void layer2_fused(
    const bf16* __restrict__ h1, const int2* __restrict__ nrng,
    const int* __restrict__ csr, const bf16* __restrict__ wlb,
    const float* __restrict__ bl, const float* __restrict__ Wlin,
    float* __restrict__ s_src, float* __restrict__ s_dst)
{
    __shared__ uint mean_l[64 * MSTRIDE];
    int nb0 = blockIdx.x * 64;
    gather_mean_lds(h1, nrng, csr, nb0, mean_l);
    __syncthreads();
    int tid = threadIdx.x;
    int wave = tid >> 6, lane = tid & 63;
    if (wave >= 4) return;
    int quad = lane >> 4, n16 = lane & 15;
    int nb = nb0 + wave * 16;
    int ln = wave * 16 + n16;

    int node_a = nb + n16;
    int na = node_a < N_NODES ? node_a : N_NODES - 1;
    short8 a[4];
#pragma unroll
    for (int c = 0; c < 2; c++)
        a[c] = *(const short8*)(mean_l + ln * MSTRIDE + c * 16 + quad * 4);
#pragma unroll
    for (int c = 0; c < 2; c++)
        a[2 + c] = load8bf(h1, (long)na * 64 + c * 32 + quad * 8);

    float sa[4] = {0.f, 0.f, 0.f, 0.f};
    float sb[4] = {0.f, 0.f, 0.f, 0.f};
#pragma unroll
    for (int t = 0; t < 4; t++) {
        int f = 16 * t + n16;
        f32x4 acc = {0.f, 0.f, 0.f, 0.f};
#pragma unroll
        for (int c = 0; c < 4; c++) {
            short8 bfr = load_bfrag(wlb, f, c, quad);
            acc = __builtin_amdgcn_mfma_f32_16x16x32_bf16(a[c], bfr, acc, 0, 0, 0);
        }
        float bias = bl[f];
        float wa = Wlin[f];
        float wb = Wlin[64 + f];
#pragma unroll
        for (int r = 0; r < 4; r++) {
            float h = fmaxf(acc[r] + bias, 0.0f);
            sa[r] += h * wa;
            sb[r] += h * wb;
        }
    }
#pragma unroll
    for (int m = 1; m < 16; m <<= 1) {
#pragma unroll
        for (int r = 0; r < 4; r++) {
            sa[r] += __shfl_xor(sa[r], m);
            sb[r] += __shfl_xor(sb[r], m);
        }
    }
    if (n16 == 0) {
#pragma unroll
        for (int r = 0; r < 4; r++) {
            int node = nb + quad * 4 + r;
            if (node < N_NODES) { s_src[node] = sa[r]; s_dst[node] = sb[r]; }
        }
    }
}

__global__ __launch_bounds__(256) void edge_out_kernel(
    const int* __restrict__ src, const int* __restrict__ dst,
    const float* __restrict__ s_src, const float* __restrict__ s_dst,
    const float* __restrict__ blin, float* __restrict__ out)
{
    int i = blockIdx.x * 256 + threadIdx.x;
    if (i >= N_EDGES / 4) return;
    int4 s4 = ((const int4*)src)[i];
    int4 d4 = ((const int4*)dst)[i];
    float b = blin[0];
    float4 o;
    o.x = s_src[s4.x] + s_dst[d4.x] + b;
    o.y = s_src[s4.y] + s_dst[d4.y] + b;
    o.z = s_src[s4.z] + s_dst[d4.z] + b;
    o.w = s_src[s4.w] + s_dst[d4.w] + b;
    ((float4*)out)[i] = o;
}

extern "C" void kernel_launch(void* const* d_in, const int* in_sizes, int n_in,
                              void* d_out, int out_size, void* d_ws, size_t ws_size,
                              hipStream_t stream) {
    const float* x    = (const float*)d_in[0];
    const int*   ei   = (const int*)d_in[1];
    const float* W1l  = (const float*)d_in[2];
    const float* b1l  = (const float*)d_in[3];
    const float* W1r  = (const float*)d_in[4];
    const float* W2l  = (const float*)d_in[5];
    const float* b2l  = (const float*)d_in[6];
    const float* W2r  = (const float*)d_in[7];
    const float* Wlin = (const float*)d_in[8];
    const float* blin = (const float*)d_in[9];
    float* out = (float*)d_out;

    const int* src = ei;
    const int* dst = ei + N_EDGES;

    // Workspace (~37 MB of 256 MiB; every byte read is written first)
    char* w = (char*)d_ws;
    bf16*  xb    = (bf16*)w;  w += (size_t)N_NODES * 64 * 2;   // 12.8 MB
    bf16*  h1    = (bf16*)w;  w += (size_t)N_NODES * 64 * 2;   // 12.8 MB
    float* ssrc  = (float*)w; w += (size_t)N_NODES * 4;
    float* sdst  = (float*)w; w += (size_t)N_NODES * 4;
    int2*  nrng  = (int2*)w;  w += (size_t)N_NODES * 8;        // 0.8 MB
    int*   gcur  = (int*)w;   w += 256 * 4;
    bf16*  wb    = (bf16*)w;  w += 16384 * 2;                  // 32 KB bf16 weights
    int*   pk    = (int*)w;   w += (size_t)NBUCK * BCAP * 4;   // 9.6 MB
    int*   csr   = (int*)w;   w += (size_t)NBUCK * BCAP * 4;   // 9.6 MB

    const int prep_blocks  = PART_BLOCKS + CONV_BLOCKS; // 6641
    const int csr_blocks   = NBUCK * 4;                 // 784
    const int fused_blocks = (N_NODES + 63) / 64;       // 1563
    const int eo_blocks    = (N_EDGES / 4 + 255) / 256; // 1563

    // ---- pk build + conversions (one concurrent grid) ----
    (void)hipMemsetAsync(gcur, 0, 256 * 4, stream);
    prep_kernel<<<prep_blocks, 256, 0, stream>>>(
        x, xb, W1l, W1r, W2l, W2r, wb, src, dst, gcur, pk);
    csr_build<<<csr_blocks, 512, 0, stream>>>(gcur, pk, csr, nrng);

    // ---- Fused layers ----
    layer1_fused<<<fused_blocks, 512, 0, stream>>>(xb, nrng, csr, wb, b1l, h1);
    layer2_fused<<<fused_blocks, 512, 0, stream>>>(h1, nrng, csr, wb + 8192, b2l, Wlin, ssrc, sdst);

    // ---- Edge scores ----
    edge_out_kernel<<<eo_blocks, 256, 0, stream>>>(src, dst, ssrc, sdst, blin, out);
}